// Round 1
// baseline (629.529 us; speedup 1.0000x reference)
//
#include <hip/hip_runtime.h>
#include <cstdint>
#include <cstddef>

typedef unsigned short u16;
typedef __attribute__((ext_vector_type(8))) short bf16x8;
typedef __attribute__((ext_vector_type(4))) float f32x4;

#define LOG2E 1.44269504088896340736f

__device__ __forceinline__ u16 f2bf(float f) {
  uint32_t u = __float_as_uint(f);
  u += 0x7fffu + ((u >> 16) & 1u);
  return (u16)(u >> 16);
}

// ---------------- transpose fp32 (K,N) -> bf16 (N,K) ----------------
__global__ __launch_bounds__(256) void transpose_w(const float* __restrict__ W,
                                                   u16* __restrict__ WT,
                                                   int K, int N) {
  __shared__ float t[32][33];
  int n0 = blockIdx.x * 32, k0 = blockIdx.y * 32;
  for (int i = threadIdx.y; i < 32; i += 8)
    t[i][threadIdx.x] = W[(size_t)(k0 + i) * N + n0 + threadIdx.x];
  __syncthreads();
  for (int i = threadIdx.y; i < 32; i += 8)
    WT[(size_t)(n0 + i) * K + k0 + threadIdx.x] = f2bf(t[threadIdx.x][i]);
}

// ---------------- layernorm fp32 row(1024) -> bf16 ----------------
__global__ __launch_bounds__(256) void ln_kernel(const float* __restrict__ x,
                                                 const float* __restrict__ g,
                                                 const float* __restrict__ b,
                                                 u16* __restrict__ out) {
  int row = blockIdx.x;
  const float4 v = *(const float4*)(x + (size_t)row * 1024 + threadIdx.x * 4);
  float s = v.x + v.y + v.z + v.w;
  float ss = v.x * v.x + v.y * v.y + v.z * v.z + v.w * v.w;
#pragma unroll
  for (int d = 1; d < 64; d <<= 1) { s += __shfl_xor(s, d); ss += __shfl_xor(ss, d); }
  __shared__ float rs_[4], rss_[4];
  int wv = threadIdx.x >> 6;
  if ((threadIdx.x & 63) == 0) { rs_[wv] = s; rss_[wv] = ss; }
  __syncthreads();
  s = rs_[0] + rs_[1] + rs_[2] + rs_[3];
  ss = rss_[0] + rss_[1] + rss_[2] + rss_[3];
  float mu = s * (1.f / 1024.f);
  float var = ss * (1.f / 1024.f) - mu * mu;
  float rstd = rsqrtf(var + 1e-5f);
  float4 gv = *(const float4*)(g + threadIdx.x * 4);
  float4 bv = *(const float4*)(b + threadIdx.x * 4);
  uint32_t lo = (uint32_t)f2bf((v.x - mu) * rstd * gv.x + bv.x) |
                ((uint32_t)f2bf((v.y - mu) * rstd * gv.y + bv.y) << 16);
  uint32_t hi = (uint32_t)f2bf((v.z - mu) * rstd * gv.z + bv.z) |
                ((uint32_t)f2bf((v.w - mu) * rstd * gv.w + bv.w) << 16);
  uint2 o; o.x = lo; o.y = hi;
  *(uint2*)(out + (size_t)row * 1024 + threadIdx.x * 4) = o;
}

// ---------------- GEMM: C = A(bf16 MxK) * B(bf16, given as BT NxK) ----------------
// MODE 0: QKV  (N=3072) -> Q[B,H,T,HD]*0.125 / K[B,H,T,HD] / VT[B,H,HD,T]
// MODE 1: PROJ -> outf = acc + bias + resid      (fp32)
// MODE 2: FF1  -> ob0  = bf16(relu(acc + bias))
// MODE 3: FF2  -> outf = relu(acc + bias) + resid (fp32)
#define BM 128
#define BN 128
#define BK 64
#define LDP 72

template <int MODE>
__global__ __launch_bounds__(256) void gemm_bt(
    const u16* __restrict__ A, const u16* __restrict__ BT,
    int M, int N, int K,
    const float* __restrict__ bias, const float* __restrict__ resid,
    float* __restrict__ outf,
    u16* __restrict__ ob0, u16* __restrict__ ob1, u16* __restrict__ ob2) {
  __shared__ u16 As[BM * LDP];
  __shared__ u16 Bs[BN * LDP];
  const int tid = threadIdx.x, lane = tid & 63;
  const int wr = (tid >> 6) >> 1, wc = (tid >> 6) & 1;
  const int bm = blockIdx.y, bn = blockIdx.x;
  const int l15 = lane & 15, lhi = lane >> 4;

  f32x4 acc[4][4];
#pragma unroll
  for (int i = 0; i < 4; ++i)
#pragma unroll
    for (int j = 0; j < 4; ++j) acc[i][j] = (f32x4){0.f, 0.f, 0.f, 0.f};

  for (int kt = 0; kt < K; kt += BK) {
    __syncthreads();
#pragma unroll
    for (int c = 0; c < 4; ++c) {
      int idx = c * 256 + tid;
      int row = idx >> 3, col = (idx & 7) * 8;
      *(bf16x8*)&As[row * LDP + col] =
          *(const bf16x8*)&A[(size_t)(bm * BM + row) * K + kt + col];
      *(bf16x8*)&Bs[row * LDP + col] =
          *(const bf16x8*)&BT[(size_t)(bn * BN + row) * K + kt + col];
    }
    __syncthreads();
#pragma unroll
    for (int ks = 0; ks < 2; ++ks) {
      bf16x8 af[4], bf[4];
#pragma unroll
      for (int i = 0; i < 4; ++i)
        af[i] = *(const bf16x8*)&As[(wr * 64 + i * 16 + l15) * LDP + ks * 32 + lhi * 8];
#pragma unroll
      for (int j = 0; j < 4; ++j)
        bf[j] = *(const bf16x8*)&Bs[(wc * 64 + j * 16 + l15) * LDP + ks * 32 + lhi * 8];
#pragma unroll
      for (int i = 0; i < 4; ++i)
#pragma unroll
        for (int j = 0; j < 4; ++j)
          acc[i][j] = __builtin_amdgcn_mfma_f32_16x16x32_bf16(af[i], bf[j], acc[i][j], 0, 0, 0);
    }
  }

#pragma unroll
  for (int i = 0; i < 4; ++i) {
#pragma unroll
    for (int j = 0; j < 4; ++j) {
      int col = bn * BN + wc * 64 + j * 16 + l15;
      int rbase = bm * BM + wr * 64 + i * 16 + lhi * 4;
#pragma unroll
      for (int r = 0; r < 4; ++r) {
        float v = acc[i][j][r];
        int rg = rbase + r;
        if (MODE == 0) {
          int b = rg >> 11, t = rg & 2047;
          int cm = col & 1023, h = cm >> 6, d = cm & 63;
          size_t bh = (size_t)(b * 16 + h);
          if (col < 1024)
            ob0[(bh * 2048 + t) * 64 + d] = f2bf(v * 0.125f);
          else if (col < 2048)
            ob1[(bh * 2048 + t) * 64 + d] = f2bf(v);
          else
            ob2[(bh * 64 + d) * 2048 + t] = f2bf(v);
        } else if (MODE == 1) {
          outf[(size_t)rg * N + col] = v + bias[col] + resid[(size_t)rg * N + col];
        } else if (MODE == 2) {
          ob0[(size_t)rg * N + col] = f2bf(fmaxf(v + bias[col], 0.f));
        } else {
          outf[(size_t)rg * N + col] = fmaxf(v + bias[col], 0.f) + resid[(size_t)rg * N + col];
        }
      }
    }
  }
}

// ---------------- causal flash attention ----------------
// Q,K: [B*H, T, 64] bf16 (Q pre-scaled by 1/8); VT: [B*H, 64, T] bf16
// O: [B*T, 1024] bf16
__global__ __launch_bounds__(256) void attn_kernel(
    const u16* __restrict__ Qb, const u16* __restrict__ Kb,
    const u16* __restrict__ VTb, u16* __restrict__ O) {
  const int qt = blockIdx.x, bh = blockIdx.y;
  const u16* Q = Qb + (size_t)bh * 2048 * 64;
  const u16* Kp = Kb + (size_t)bh * 2048 * 64;
  const u16* VT = VTb + (size_t)bh * 64 * 2048;
  const int tid = threadIdx.x, lane = tid & 63, wv = tid >> 6;
  const int l15 = lane & 15, lhi = lane >> 4;

  __shared__ u16 Ks[64 * 72];
  __shared__ u16 Vs[64 * 72];
  __shared__ u16 Ps[4][16 * 72];

  bf16x8 qf[2];
#pragma unroll
  for (int s = 0; s < 2; ++s)
    qf[s] = *(const bf16x8*)&Q[(size_t)(qt * 64 + wv * 16 + l15) * 64 + s * 32 + lhi * 8];

  f32x4 o[4];
#pragma unroll
  for (int f = 0; f < 4; ++f) o[f] = (f32x4){0.f, 0.f, 0.f, 0.f};
  float m[4] = {-1e30f, -1e30f, -1e30f, -1e30f};
  float l[4] = {0.f, 0.f, 0.f, 0.f};

  for (int kt = 0; kt <= qt; ++kt) {
    __syncthreads();
#pragma unroll
    for (int c = 0; c < 2; ++c) {
      int idx = c * 256 + tid;
      int row = idx >> 3, colc = (idx & 7) * 8;
      *(bf16x8*)&Ks[row * 72 + colc] =
          *(const bf16x8*)&Kp[(size_t)(kt * 64 + row) * 64 + colc];
      *(bf16x8*)&Vs[row * 72 + colc] =
          *(const bf16x8*)&VT[(size_t)row * 2048 + kt * 64 + colc];
    }
    __syncthreads();

    f32x4 s[4];
#pragma unroll
    for (int j = 0; j < 4; ++j) s[j] = (f32x4){0.f, 0.f, 0.f, 0.f};
#pragma unroll
    for (int ks = 0; ks < 2; ++ks) {
#pragma unroll
      for (int j = 0; j < 4; ++j) {
        bf16x8 kf = *(const bf16x8*)&Ks[(j * 16 + l15) * 72 + ks * 32 + lhi * 8];
        s[j] = __builtin_amdgcn_mfma_f32_16x16x32_bf16(qf[ks], kf, s[j], 0, 0, 0);
      }
    }

    if (kt == qt) {
#pragma unroll
      for (int j = 0; j < 4; ++j)
#pragma unroll
        for (int r = 0; r < 4; ++r) {
          int rl = wv * 16 + lhi * 4 + r, cl = j * 16 + l15;
          if (cl > rl) s[j][r] = -1e30f;
        }
    }

    float p[4][4];
#pragma unroll
    for (int r = 0; r < 4; ++r) {
      float pm = fmaxf(fmaxf(s[0][r], s[1][r]), fmaxf(s[2][r], s[3][r]));
#pragma unroll
      for (int d = 1; d < 16; d <<= 1) pm = fmaxf(pm, __shfl_xor(pm, d));
      float mn = fmaxf(m[r], pm);
      float sc = exp2f((m[r] - mn) * LOG2E);
      float rowsum = 0.f;
#pragma unroll
      for (int j = 0; j < 4; ++j) {
        float pv = exp2f((s[j][r] - mn) * LOG2E);
        p[j][r] = pv;
        rowsum += pv;
      }
#pragma unroll
      for (int d = 1; d < 16; d <<= 1) rowsum += __shfl_xor(rowsum, d);
      l[r] = l[r] * sc + rowsum;
      m[r] = mn;
#pragma unroll
      for (int f = 0; f < 4; ++f) o[f][r] *= sc;
    }

#pragma unroll
    for (int j = 0; j < 4; ++j)
#pragma unroll
      for (int r = 0; r < 4; ++r)
        Ps[wv][(lhi * 4 + r) * 72 + j * 16 + l15] = f2bf(p[j][r]);
    __syncthreads();

#pragma unroll
    for (int ks = 0; ks < 2; ++ks) {
      bf16x8 pf = *(const bf16x8*)&Ps[wv][l15 * 72 + ks * 32 + lhi * 8];
#pragma unroll
      for (int f = 0; f < 4; ++f) {
        bf16x8 vfr = *(const bf16x8*)&Vs[(f * 16 + l15) * 72 + ks * 32 + lhi * 8];
        o[f] = __builtin_amdgcn_mfma_f32_16x16x32_bf16(pf, vfr, o[f], 0, 0, 0);
      }
    }
  }

  const int b = bh >> 4, h = bh & 15;
#pragma unroll
  for (int r = 0; r < 4; ++r) {
    float inv = 1.f / l[r];
    int t = qt * 64 + wv * 16 + lhi * 4 + r;
#pragma unroll
    for (int f = 0; f < 4; ++f)
      O[((size_t)(b * 2048 + t)) * 1024 + h * 64 + f * 16 + l15] = f2bf(o[f][r] * inv);
  }
}

extern "C" void kernel_launch(void* const* d_in, const int* in_sizes, int n_in,
                              void* d_out, int out_size, void* d_ws, size_t ws_size,
                              hipStream_t stream) {
  const float* x   = (const float*)d_in[0];
  const float* Wq  = (const float*)d_in[1];
  const float* Wk  = (const float*)d_in[2];
  const float* Wv  = (const float*)d_in[3];
  const float* Wo  = (const float*)d_in[4];
  const float* bo  = (const float*)d_in[5];
  const float* W1  = (const float*)d_in[6];
  const float* b1  = (const float*)d_in[7];
  const float* W2  = (const float*)d_in[8];
  const float* b2  = (const float*)d_in[9];
  const float* g1  = (const float*)d_in[10];
  const float* be1 = (const float*)d_in[11];
  const float* g2  = (const float*)d_in[12];
  const float* be2 = (const float*)d_in[13];

  char* p = (char*)d_ws;
  auto alloc = [&](size_t bytes) {
    char* r = p;
    p += (bytes + 255) & ~(size_t)255;
    return r;
  };
  u16* WqkvT = (u16*)alloc(3072ull * 1024 * 2);
  u16* WoT   = (u16*)alloc(1024ull * 1024 * 2);
  u16* W1T   = (u16*)alloc(4096ull * 1024 * 2);
  u16* W2T   = (u16*)alloc(1024ull * 4096 * 2);
  u16* hln   = (u16*)alloc(8192ull * 1024 * 2);
  u16* Qbuf  = (u16*)alloc(8192ull * 1024 * 2);
  u16* Kbuf  = (u16*)alloc(8192ull * 1024 * 2);
  u16* VTbuf = (u16*)alloc(8192ull * 1024 * 2);
  float* x2  = (float*)alloc(8192ull * 1024 * 4);
  u16* ff1   = (u16*)alloc(8192ull * 4096 * 2);
  u16* Oattn = hln;   // hln dead after QKV GEMM
  u16* h2    = Qbuf;  // Qbuf dead after attention
  if ((size_t)(p - (char*)d_ws) > ws_size) return;  // ws too small: bail

  dim3 tb(32, 8);
  transpose_w<<<dim3(32, 32), tb, 0, stream>>>(Wq, WqkvT, 1024, 1024);
  transpose_w<<<dim3(32, 32), tb, 0, stream>>>(Wk, WqkvT + 1024 * 1024, 1024, 1024);
  transpose_w<<<dim3(32, 32), tb, 0, stream>>>(Wv, WqkvT + 2048 * 1024, 1024, 1024);
  transpose_w<<<dim3(32, 32), tb, 0, stream>>>(Wo, WoT, 1024, 1024);
  transpose_w<<<dim3(128, 32), tb, 0, stream>>>(W1, W1T, 1024, 4096);
  transpose_w<<<dim3(32, 128), tb, 0, stream>>>(W2, W2T, 4096, 1024);

  ln_kernel<<<8192, 256, 0, stream>>>(x, g1, be1, hln);

  gemm_bt<0><<<dim3(24, 64), 256, 0, stream>>>(hln, WqkvT, 8192, 3072, 1024,
                                               nullptr, nullptr, nullptr,
                                               Qbuf, Kbuf, VTbuf);

  attn_kernel<<<dim3(32, 64), 256, 0, stream>>>(Qbuf, Kbuf, VTbuf, Oattn);

  gemm_bt<1><<<dim3(8, 64), 256, 0, stream>>>(Oattn, WoT, 8192, 1024, 1024,
                                              bo, x, x2, nullptr, nullptr, nullptr);

  ln_kernel<<<8192, 256, 0, stream>>>(x2, g2, be2, h2);

  gemm_bt<2><<<dim3(32, 64), 256, 0, stream>>>(h2, W1T, 8192, 4096, 1024,
                                               b1, nullptr, nullptr, ff1, nullptr, nullptr);

  gemm_bt<3><<<dim3(8, 64), 256, 0, stream>>>(ff1, W2T, 8192, 1024, 4096,
                                              b2, x2, (float*)d_out, nullptr, nullptr, nullptr);
}